// Round 1
// baseline (36950.577 us; speedup 1.0000x reference)
//
#include <hip/hip_runtime.h>
#include <hip/hip_bf16.h>
#include <hip/hip_cooperative_groups.h>

namespace cg = cooperative_groups;
typedef __hip_bfloat16 bf16;

#define NB 64
#define NS 256
#define ND 512
#define NHE 512
#define NHD 1024
#define NGE 1536
#define NGD 3072

static __device__ __forceinline__ float sigmf(float x){ return 1.0f/(1.0f+__expf(-x)); }

// ---------------- small prep kernels ----------------
__global__ __launch_bounds__(256) void k_sx(const float* __restrict__ x,
                                            const float* __restrict__ attnW,
                                            const float* __restrict__ attnb,
                                            float* __restrict__ sx){
    int row = blockIdx.x*4 + (threadIdx.x>>6);     // row = b*256+t
    int lane = threadIdx.x & 63;
    float s = 0.f;
    for (int d = lane; d < ND; d += 64) s += x[(size_t)row*ND + d]*attnW[d];
    #pragma unroll
    for (int off = 32; off; off >>= 1) s += __shfl_down(s, off, 64);
    if (lane == 0) sx[row] = s + attnb[0];
}

__global__ __launch_bounds__(256) void k_cvec(const float* __restrict__ dWih,
                                              const float* __restrict__ linb,
                                              const float* __restrict__ dbih,
                                              float* __restrict__ cvec){
    int row = blockIdx.x*4 + (threadIdx.x>>6);     // 0..3071
    int lane = threadIdx.x & 63;
    float s = 0.f;
    for (int d = lane; d < ND; d += 64) s += dWih[(size_t)row*ND + d]*linb[d];
    #pragma unroll
    for (int off = 32; off; off >>= 1) s += __shfl_down(s, off, 64);
    if (lane == 0) cvec[row] = s + dbih[row];
}

__global__ __launch_bounds__(256) void k_softprep(const float* __restrict__ sx,
                                                  float* __restrict__ e,
                                                  float* __restrict__ Se){
    int b = blockIdx.x, s = threadIdx.x;
    __shared__ float red[256];
    float v = sx[b*NS + s];
    red[s] = v; __syncthreads();
    for (int off = 128; off; off >>= 1){ if (s < off) red[s] = fmaxf(red[s], red[s+off]); __syncthreads(); }
    float mx = red[0]; __syncthreads();
    float ev = __expf(v - mx);
    e[b*NS + s] = ev;
    red[s] = ev; __syncthreads();
    for (int off = 128; off; off >>= 1){ if (s < off) red[s] += red[s+off]; __syncthreads(); }
    if (s == 0) Se[b] = red[0];
}

__global__ __launch_bounds__(256) void k_zexp(const float4* __restrict__ mu4,
                                              const float4* __restrict__ lv4,
                                              const float4* __restrict__ eps4,
                                              bf16* __restrict__ z){
    size_t i = (size_t)blockIdx.x*256 + threadIdx.x;
    float4 m = mu4[i], l = lv4[i], e = eps4[i];
    size_t o = i*4;
    z[o+0] = __float2bfloat16(m.x + e.x*__expf(0.5f*l.x));
    z[o+1] = __float2bfloat16(m.y + e.y*__expf(0.5f*l.y));
    z[o+2] = __float2bfloat16(m.z + e.z*__expf(0.5f*l.z));
    z[o+3] = __float2bfloat16(m.w + e.w*__expf(0.5f*l.w));
}

__global__ __launch_bounds__(256) void k_T(const bf16* __restrict__ z,
                                           const float* __restrict__ e,
                                           float* __restrict__ T){
    int b = blockIdx.x;
    int h = blockIdx.y*256 + threadIdx.x;
    __shared__ float es[256];
    es[threadIdx.x] = e[b*NS + threadIdx.x];
    __syncthreads();
    float acc = 0.f;
    for (int s = 0; s < NS; ++s)
        acc += es[s]*__bfloat162float(z[((size_t)b*NS + s)*NHD + h]);
    T[b*NHD + h] = acc;
}

__global__ __launch_bounds__(256) void k_ctx(const bf16* __restrict__ z,
                                             const float* __restrict__ e,
                                             const float* __restrict__ Se,
                                             const float* __restrict__ T,
                                             bf16* __restrict__ ctxT){
    int i = blockIdx.x;
    int h0 = blockIdx.y*16;
    int b = threadIdx.x & 63;
    int tc = threadIdx.x >> 6;
    float ei = e[b*NS + i];
    float inv = 1.0f/(Se[b] - ei);
    #pragma unroll
    for (int l = 0; l < 4; ++l){
        int h = h0 + tc*4 + l;
        float zv = __bfloat162float(z[((size_t)b*NS + i)*NHD + h]);
        float cv = (T[b*NHD + h] - ei*zv)*inv;
        ctxT[((size_t)i*NHD + h)*NB + b] = __float2bfloat16(cv);
    }
}

// ---------------- GEMM kernels (fp32 VALU, 64x64 tiles, 4x4/thread) ----------------
// Xg[dir][t][g][b] = x[b,t,:] @ Wih[dir].T + bih[dir]   (stored bf16)
__global__ __launch_bounds__(256) void k_gemm_xg(
    const float* __restrict__ x,
    const float* __restrict__ W0, const float* __restrict__ W1,
    const float* __restrict__ W2, const float* __restrict__ W3,
    const float* __restrict__ b0, const float* __restrict__ b1,
    const float* __restrict__ b2, const float* __restrict__ b3,
    bf16* __restrict__ Xg){
    int t = blockIdx.x;
    int g0 = blockIdx.y*64;
    int dir = blockIdx.z;
    const float* W   = dir==0?W0:dir==1?W1:dir==2?W2:W3;
    const float* bih = dir==0?b0:dir==1?b1:dir==2?b2:b3;
    __shared__ float As[64][36];
    __shared__ float Bs[64][36];
    int tid = threadIdx.x, tx = tid & 15, ty = tid >> 4;
    float acc[4][4] = {};
    for (int k0 = 0; k0 < ND; k0 += 32){
        #pragma unroll
        for (int m = 0; m < 8; ++m){
            int idx = m*256 + tid;
            int row = idx >> 5, kk = idx & 31;
            As[row][kk] = x[((size_t)row*NS + t)*ND + k0 + kk];
            Bs[row][kk] = W[(size_t)(g0+row)*ND + k0 + kk];
        }
        __syncthreads();
        #pragma unroll
        for (int k4 = 0; k4 < 8; ++k4){
            float4 a[4], bb[4];
            #pragma unroll
            for (int i = 0; i < 4; ++i) a[i]  = *(const float4*)&As[ty*4+i][k4*4];
            #pragma unroll
            for (int j = 0; j < 4; ++j) bb[j] = *(const float4*)&Bs[tx*4+j][k4*4];
            #pragma unroll
            for (int i = 0; i < 4; ++i)
                #pragma unroll
                for (int j = 0; j < 4; ++j)
                    acc[i][j] += a[i].x*bb[j].x + a[i].y*bb[j].y + a[i].z*bb[j].z + a[i].w*bb[j].w;
        }
        __syncthreads();
    }
    size_t base = ((size_t)(dir*NS + t)*NGE + g0)*NB;
    #pragma unroll
    for (int j = 0; j < 4; ++j){
        float bi = bih[g0 + tx*4 + j];
        #pragma unroll
        for (int i = 0; i < 4; ++i)
            Xg[base + (size_t)(tx*4+j)*NB + ty*4 + i] = __float2bfloat16(acc[i][j] + bi);
    }
}

// Gctx[i][g][b] = ctx[i,b,:] @ dec_Whh.T + dec_bhh   (A from ctxT bf16 [i][h][b])
__global__ __launch_bounds__(256) void k_gemm_gctx(
    const bf16* __restrict__ ctxT,
    const float* __restrict__ Whh,
    const float* __restrict__ bhh,
    bf16* __restrict__ Gctx){
    int i = blockIdx.x;
    int g0 = blockIdx.y*64;
    __shared__ float As[64][36];   // [b][k]
    __shared__ float Bs[64][36];   // [g][k]
    int tid = threadIdx.x, tx = tid & 15, ty = tid >> 4;
    float acc[4][4] = {};
    for (int k0 = 0; k0 < NHD; k0 += 32){
        #pragma unroll
        for (int m = 0; m < 8; ++m){
            int idx = m*256 + tid;
            int bb2 = idx & 63, kk = idx >> 6;
            As[bb2][kk] = __bfloat162float(ctxT[((size_t)i*NHD + k0 + kk)*NB + bb2]);
            int row = idx >> 5, k2 = idx & 31;
            Bs[row][k2] = Whh[(size_t)(g0+row)*NHD + k0 + k2];
        }
        __syncthreads();
        #pragma unroll
        for (int k4 = 0; k4 < 8; ++k4){
            float4 a[4], bb[4];
            #pragma unroll
            for (int i2 = 0; i2 < 4; ++i2) a[i2]  = *(const float4*)&As[ty*4+i2][k4*4];
            #pragma unroll
            for (int j = 0; j < 4; ++j)   bb[j] = *(const float4*)&Bs[tx*4+j][k4*4];
            #pragma unroll
            for (int i2 = 0; i2 < 4; ++i2)
                #pragma unroll
                for (int j = 0; j < 4; ++j)
                    acc[i2][j] += a[i2].x*bb[j].x + a[i2].y*bb[j].y + a[i2].z*bb[j].z + a[i2].w*bb[j].w;
        }
        __syncthreads();
    }
    size_t base = ((size_t)i*NGD + g0)*NB;
    #pragma unroll
    for (int j = 0; j < 4; ++j){
        float bi = bhh[g0 + tx*4 + j];
        #pragma unroll
        for (int i2 = 0; i2 < 4; ++i2)
            Gctx[base + (size_t)(tx*4+j)*NB + ty*4 + i2] = __float2bfloat16(acc[i2][j] + bi);
    }
}

// rec[b,i,:] = H[i,:,b] @ lin_W.T + lin_b
__global__ __launch_bounds__(256) void k_gemm_rec(
    const float* __restrict__ H,       // [i][k][b]
    const float* __restrict__ linW,    // [512][1024]
    const float* __restrict__ linb,
    float* __restrict__ outRec){
    int i = blockIdx.x;
    int d0 = blockIdx.y*64;
    __shared__ float As[64][36];
    __shared__ float Bs[64][36];
    int tid = threadIdx.x, tx = tid & 15, ty = tid >> 4;
    float acc[4][4] = {};
    for (int k0 = 0; k0 < NHD; k0 += 32){
        #pragma unroll
        for (int m = 0; m < 8; ++m){
            int idx = m*256 + tid;
            int bb2 = idx & 63, kk = idx >> 6;
            As[bb2][kk] = H[((size_t)i*NHD + k0 + kk)*NB + bb2];
            int row = idx >> 5, k2 = idx & 31;
            Bs[row][k2] = linW[(size_t)(d0+row)*NHD + k0 + k2];
        }
        __syncthreads();
        #pragma unroll
        for (int k4 = 0; k4 < 8; ++k4){
            float4 a[4], bb[4];
            #pragma unroll
            for (int i2 = 0; i2 < 4; ++i2) a[i2]  = *(const float4*)&As[ty*4+i2][k4*4];
            #pragma unroll
            for (int j = 0; j < 4; ++j)   bb[j] = *(const float4*)&Bs[tx*4+j][k4*4];
            #pragma unroll
            for (int i2 = 0; i2 < 4; ++i2)
                #pragma unroll
                for (int j = 0; j < 4; ++j)
                    acc[i2][j] += a[i2].x*bb[j].x + a[i2].y*bb[j].y + a[i2].z*bb[j].z + a[i2].w*bb[j].w;
        }
        __syncthreads();
    }
    #pragma unroll
    for (int j = 0; j < 4; ++j){
        float lb = linb[d0 + tx*4 + j];
        #pragma unroll
        for (int i2 = 0; i2 < 4; ++i2){
            int bb2 = ty*4 + i2;
            outRec[((size_t)bb2*NS + i)*ND + d0 + tx*4 + j] = acc[i2][j] + lb;
        }
    }
}

// M[g][h] = dec_Wih @ lin_W  (3072x1024, K=512)
__global__ __launch_bounds__(256) void k_gemm_M(
    const float* __restrict__ dWih,
    const float* __restrict__ linW,
    float* __restrict__ M){
    int g0 = blockIdx.x*64;
    int h0 = blockIdx.y*64;
    __shared__ float As[64][36];   // [g][k]
    __shared__ float Bs[32][68];   // [k][h]
    int tid = threadIdx.x, tx = tid & 15, ty = tid >> 4;
    float acc[4][4] = {};
    for (int k0 = 0; k0 < ND; k0 += 32){
        #pragma unroll
        for (int m = 0; m < 8; ++m){
            int idx = m*256 + tid;
            int row = idx >> 5, kk = idx & 31;
            As[row][kk] = dWih[(size_t)(g0+row)*ND + k0 + kk];
            int k2 = idx >> 6, hh = idx & 63;
            if (m < 8) Bs[k2][hh] = linW[(size_t)(k0+k2)*NHD + h0 + hh];
        }
        __syncthreads();
        for (int k = 0; k < 32; ++k){
            float a[4];
            #pragma unroll
            for (int i = 0; i < 4; ++i) a[i] = As[ty*4+i][k];
            float4 b4 = *(const float4*)&Bs[k][tx*4];
            #pragma unroll
            for (int i = 0; i < 4; ++i){
                acc[i][0] += a[i]*b4.x; acc[i][1] += a[i]*b4.y;
                acc[i][2] += a[i]*b4.z; acc[i][3] += a[i]*b4.w;
            }
        }
        __syncthreads();
    }
    #pragma unroll
    for (int i = 0; i < 4; ++i)
        #pragma unroll
        for (int j = 0; j < 4; ++j)
            M[(size_t)(g0+ty*4+i)*NHD + h0 + tx*4 + j] = acc[i][j];
}

// ---------------- persistent cooperative recurrence kernels ----------------
// encoder: 4 dirs x 64 colgroups; thread (b, tc) owns h-cols j0,j0+1 of its group
__global__ __launch_bounds__(256) void k_encoder(
    const bf16* __restrict__ Xg,
    const float* __restrict__ W0, const float* __restrict__ W1,
    const float* __restrict__ W2, const float* __restrict__ W3,
    const float* __restrict__ h0v, const float* __restrict__ h1v,
    const float* __restrict__ h2v, const float* __restrict__ h3v,
    float* __restrict__ henc,      // [2][4][512][64]
    float* __restrict__ outMu,
    float* __restrict__ outLv){
    cg::grid_group grid = cg::this_grid();
    int wg  = blockIdx.x;
    int dir = wg >> 6;
    int grp = wg & 63;
    int b   = threadIdx.x & 63;
    int tc  = __builtin_amdgcn_readfirstlane(threadIdx.x >> 6);
    int j0  = grp*8 + tc*2;
    const float* Whh = dir==0?W0:dir==1?W1:dir==2?W2:W3;
    const float* bhh = dir==0?h0v:dir==1?h1v:dir==2?h2v:h3v;
    float* outp = (dir < 2) ? outMu : outLv;
    int colshift = (dir & 1)*512;

    __shared__ float hs[64][72];

    { // zero both henc buffers: 262144 floats over 65536 threads * 4
        size_t gid = ((size_t)wg*256 + threadIdx.x)*4;
        float4 zz = {0.f,0.f,0.f,0.f};
        *(float4*)(henc + gid) = zz;
    }
    grid.sync();

    for (int t = 0; t < NS; ++t){
        int pb = t & 1, nb = pb ^ 1;
        int t_in = (dir & 1) ? (255 - t) : t;
        const float* hp = henc + (size_t)(pb*4 + dir)*NHE*NB;
        float acc[6] = {0,0,0,0,0,0};
        for (int k0 = 0; k0 < NHE; k0 += 64){
            __syncthreads();
            #pragma unroll
            for (int m = 0; m < 16; ++m){
                int idx = m*256 + threadIdx.x;
                int kk = idx >> 6, bb2 = idx & 63;
                hs[bb2][kk] = hp[(size_t)(k0+kk)*NB + bb2];
            }
            __syncthreads();
            #pragma unroll 4
            for (int k4 = 0; k4 < 16; ++k4){
                float4 hv = *(const float4*)&hs[b][k4*4];
                #pragma unroll
                for (int u = 0; u < 2; ++u)
                    #pragma unroll
                    for (int p = 0; p < 3; ++p){
                        int col = j0 + u + p*512;
                        float4 wv = *(const float4*)&Whh[(size_t)col*NHE + k0 + k4*4];
                        acc[u*3+p] += hv.x*wv.x + hv.y*wv.y + hv.z*wv.z + hv.w*wv.w;
                    }
            }
        }
        size_t xgbase = ((size_t)(dir*NS + t_in)*NGE)*NB + b;
        #pragma unroll
        for (int u = 0; u < 2; ++u){
            int j = j0 + u;
            float ghr = acc[u*3+0] + bhh[j];
            float ghz = acc[u*3+1] + bhh[j+512];
            float ghn = acc[u*3+2] + bhh[j+1024];
            float gir = __bfloat162float(Xg[xgbase + (size_t)j*NB]);
            float giz = __bfloat162float(Xg[xgbase + (size_t)(j+512)*NB]);
            float gin = __bfloat162float(Xg[xgbase + (size_t)(j+1024)*NB]);
            float r  = sigmf(gir + ghr);
            float zg = sigmf(giz + ghz);
            float n  = tanhf(gin + r*ghn);
            float hprev = hp[(size_t)j*NB + b];
            float hn = (1.0f - zg)*n + zg*hprev;
            henc[((size_t)(nb*4 + dir)*NHE + j)*NB + b] = hn;
            outp[((size_t)b*NS + t_in)*NHD + colshift + j] = hn;
        }
        grid.sync();
    }
}

// decoder: 256 WGs x 4 h-cols; gi via M-composition; 1 grid.sync per step
__global__ __launch_bounds__(256) void k_decoder(
    const float* __restrict__ M,
    const float* __restrict__ cvec,
    const float* __restrict__ dbih,
    const bf16* __restrict__ Gctx,
    const bf16* __restrict__ ctxT,
    float* __restrict__ H){
    cg::grid_group grid = cg::this_grid();
    int wg = blockIdx.x;
    int b  = threadIdx.x & 63;
    int tc = __builtin_amdgcn_readfirstlane(threadIdx.x >> 6);
    int j  = wg*4 + tc;
    __shared__ float hs[64][72];

    for (int i = 0; i < NS; ++i){
        float gi[3];
        if (i == 0){
            #pragma unroll
            for (int p = 0; p < 3; ++p) gi[p] = dbih[j + p*NHD];
        } else {
            float acc[3] = {0,0,0};
            const float* hp = H + (size_t)(i-1)*NHD*NB;
            for (int k0 = 0; k0 < NHD; k0 += 64){
                __syncthreads();
                #pragma unroll
                for (int m = 0; m < 16; ++m){
                    int idx = m*256 + threadIdx.x;
                    int kk = idx >> 6, bb2 = idx & 63;
                    hs[bb2][kk] = hp[(size_t)(k0+kk)*NB + bb2];
                }
                __syncthreads();
                #pragma unroll 4
                for (int k4 = 0; k4 < 16; ++k4){
                    float4 hv = *(const float4*)&hs[b][k4*4];
                    #pragma unroll
                    for (int p = 0; p < 3; ++p){
                        float4 wv = *(const float4*)&M[(size_t)(j + p*NHD)*NHD + k0 + k4*4];
                        acc[p] += hv.x*wv.x + hv.y*wv.y + hv.z*wv.z + hv.w*wv.w;
                    }
                }
            }
            #pragma unroll
            for (int p = 0; p < 3; ++p) gi[p] = acc[p] + cvec[j + p*NHD];
        }
        size_t gb = ((size_t)i*NGD)*NB + b;
        float ghr = __bfloat162float(Gctx[gb + (size_t)j*NB]);
        float ghz = __bfloat162float(Gctx[gb + (size_t)(j+NHD)*NB]);
        float ghn = __bfloat162float(Gctx[gb + (size_t)(j+2*NHD)*NB]);
        float ctxv = __bfloat162float(ctxT[((size_t)i*NHD + j)*NB + b]);
        float r  = sigmf(gi[0] + ghr);
        float zg = sigmf(gi[1] + ghz);
        float n  = tanhf(gi[2] + r*ghn);
        float hn = (1.0f - zg)*n + zg*ctxv;
        H[((size_t)i*NHD + j)*NB + b] = hn;
        grid.sync();
    }
}

// ---------------- host launcher ----------------
extern "C" void kernel_launch(void* const* d_in, const int* in_sizes, int n_in,
                              void* d_out, int out_size, void* d_ws, size_t ws_size,
                              hipStream_t stream){
    const float* x   = (const float*)d_in[0];
    const float* eps = (const float*)d_in[1];
    const float* Wih[4]; const float* Whh[4]; const float* bih[4]; const float* bhh[4];
    for (int d = 0; d < 4; ++d){
        Wih[d] = (const float*)d_in[2 + 4*d];
        Whh[d] = (const float*)d_in[3 + 4*d];
        bih[d] = (const float*)d_in[4 + 4*d];
        bhh[d] = (const float*)d_in[5 + 4*d];
    }
    const float* dWih  = (const float*)d_in[18];
    const float* dWhh  = (const float*)d_in[19];
    const float* dbih  = (const float*)d_in[20];
    const float* dbhh  = (const float*)d_in[21];
    const float* attnW = (const float*)d_in[22];
    const float* attnb = (const float*)d_in[23];
    const float* linW  = (const float*)d_in[24];
    const float* linb  = (const float*)d_in[25];

    float* out    = (float*)d_out;
    float* outRec = out;
    float* outMu  = out + 8388608;
    float* outLv  = out + 25165824;

    char* ws = (char*)d_ws;
    bf16*  Xg    = (bf16*)(ws + 0);              // 201326592
    bf16*  Gctx  = (bf16*)(ws + 201326592);      // 100663296
    bf16*  ctxT  = (bf16*)(ws + 302989888 - 1000000);  // see below (explicit)
    // explicit offsets:
    ctxT         = (bf16*)(ws + 301989888);      // 33554432
    bf16*  zbuf  = (bf16*)(ws + 335544320);      // 33554432
    float* Hdec  = (float*)(ws + 369098752);     // 67108864
    float* Mbuf  = (float*)(ws + 436207616);     // 12582912
    float* henc  = (float*)(ws + 448790528);     // 1048576
    float* sx    = (float*)(ws + 449839104);     // 65536
    float* ebuf  = (float*)(ws + 449904640);     // 65536
    float* Se    = (float*)(ws + 449970176);     // 4096
    float* Tbuf  = (float*)(ws + 449974272);     // 262144
    float* cvec  = (float*)(ws + 450236416);     // 16384

    // phase 0: parallel prep
    hipLaunchKernelGGL(k_gemm_M, dim3(48,16), dim3(256), 0, stream, dWih, linW, Mbuf);
    hipLaunchKernelGGL(k_cvec, dim3(768), dim3(256), 0, stream, dWih, linb, dbih, cvec);
    hipLaunchKernelGGL(k_sx, dim3(4096), dim3(256), 0, stream, x, attnW, attnb, sx);
    hipLaunchKernelGGL(k_softprep, dim3(64), dim3(256), 0, stream, sx, ebuf, Se);
    hipLaunchKernelGGL(k_gemm_xg, dim3(256,24,4), dim3(256), 0, stream,
                       x, Wih[0], Wih[1], Wih[2], Wih[3], bih[0], bih[1], bih[2], bih[3], Xg);

    // phase 1: encoder recurrence (writes mu/logvar)
    {
        void* a[] = { (void*)&Xg, (void*)&Whh[0], (void*)&Whh[1], (void*)&Whh[2], (void*)&Whh[3],
                      (void*)&bhh[0], (void*)&bhh[1], (void*)&bhh[2], (void*)&bhh[3],
                      (void*)&henc, (void*)&outMu, (void*)&outLv };
        hipLaunchCooperativeKernel((void*)k_encoder, dim3(256), dim3(256), a, 0, stream);
    }

    // phase 2: z, attention statics, Gctx
    hipLaunchKernelGGL(k_zexp, dim3(16384), dim3(256), 0, stream,
                       (const float4*)outMu, (const float4*)outLv, (const float4*)eps, zbuf);
    hipLaunchKernelGGL(k_T, dim3(64,4), dim3(256), 0, stream, zbuf, ebuf, Tbuf);
    hipLaunchKernelGGL(k_ctx, dim3(256,64), dim3(256), 0, stream, zbuf, ebuf, Se, Tbuf, ctxT);
    hipLaunchKernelGGL(k_gemm_gctx, dim3(256,48), dim3(256), 0, stream, ctxT, dWhh, dbhh, Gctx);

    // phase 3: decoder recurrence
    {
        void* a[] = { (void*)&Mbuf, (void*)&cvec, (void*)&dbih, (void*)&Gctx, (void*)&ctxT, (void*)&Hdec };
        hipLaunchCooperativeKernel((void*)k_decoder, dim3(256), dim3(256), a, 0, stream);
    }

    // phase 4: output projection
    hipLaunchKernelGGL(k_gemm_rec, dim3(256,8), dim3(256), 0, stream, Hdec, linW, linb, outRec);
}

// Round 2
// 33016.360 us; speedup vs baseline: 1.1192x; 1.1192x over previous
//
#include <hip/hip_runtime.h>
#include <hip/hip_bf16.h>
#include <hip/hip_cooperative_groups.h>

namespace cg = cooperative_groups;
typedef __hip_bfloat16 bf16;

#define NB 64
#define NS 256
#define ND 512
#define NHE 512
#define NHD 1024
#define NGE 1536
#define NGD 3072

static __device__ __forceinline__ float sigmf(float x){ return 1.0f/(1.0f+__expf(-x)); }

// ---------------- small prep kernels ----------------
__global__ __launch_bounds__(256) void k_sx(const float* __restrict__ x,
                                            const float* __restrict__ attnW,
                                            const float* __restrict__ attnb,
                                            float* __restrict__ sx){
    int row = blockIdx.x*4 + (threadIdx.x>>6);     // row = b*256+t
    int lane = threadIdx.x & 63;
    float s = 0.f;
    for (int d = lane; d < ND; d += 64) s += x[(size_t)row*ND + d]*attnW[d];
    #pragma unroll
    for (int off = 32; off; off >>= 1) s += __shfl_down(s, off, 64);
    if (lane == 0) sx[row] = s + attnb[0];
}

__global__ __launch_bounds__(256) void k_cvec(const float* __restrict__ dWih,
                                              const float* __restrict__ linb,
                                              const float* __restrict__ dbih,
                                              float* __restrict__ cvec){
    int row = blockIdx.x*4 + (threadIdx.x>>6);     // 0..3071
    int lane = threadIdx.x & 63;
    float s = 0.f;
    for (int d = lane; d < ND; d += 64) s += dWih[(size_t)row*ND + d]*linb[d];
    #pragma unroll
    for (int off = 32; off; off >>= 1) s += __shfl_down(s, off, 64);
    if (lane == 0) cvec[row] = s + dbih[row];
}

// e stored transposed: esb[s][b]
__global__ __launch_bounds__(256) void k_softprep2(const float* __restrict__ sx,
                                                   float* __restrict__ esb,
                                                   float* __restrict__ Se){
    int b = blockIdx.x, s = threadIdx.x;
    __shared__ float red[256];
    float v = sx[b*NS + s];
    red[s] = v; __syncthreads();
    for (int off = 128; off; off >>= 1){ if (s < off) red[s] = fmaxf(red[s], red[s+off]); __syncthreads(); }
    float mx = red[0]; __syncthreads();
    float ev = __expf(v - mx);
    esb[s*NB + b] = ev;
    red[s] = ev; __syncthreads();
    for (int off = 128; off; off >>= 1){ if (s < off) red[s] += red[s+off]; __syncthreads(); }
    if (s == 0) Se[b] = red[0];
}

// z[t][h][b] = mu + eps*exp(0.5*lv); mu/lv read from hh[dir][t][j][b]
__global__ __launch_bounds__(256) void k_zexp2(const float* __restrict__ hh,
                                               const float* __restrict__ eps,
                                               bf16* __restrict__ z){
    int t  = blockIdx.x >> 4;
    int hb = blockIdx.x & 15;
    int h0 = hb*64;
    __shared__ float ls[64*69];
    int tid = threadIdx.x;
    #pragma unroll
    for (int q = 0; q < 16; ++q){
        int bb = q*4 + (tid>>6);
        int hc = tid & 63;
        ls[bb*69 + hc] = eps[((size_t)bb*NS + t)*NHD + h0 + hc];
    }
    __syncthreads();
    int b = tid & 63;
    #pragma unroll
    for (int q = 0; q < 16; ++q){
        int hq = q*4 + (tid>>6);
        int h = h0 + hq;
        int dmu = h >> 9;
        int jm  = h & 511;
        float mu = hh[(((size_t)(dmu*NS) + t)*NHE + jm)*NB + b];
        float lv = hh[(((size_t)((2+dmu)*NS) + t)*NHE + jm)*NB + b];
        float ep = ls[b*69 + hq];
        float zv = mu + ep*__expf(0.5f*lv);
        z[((size_t)t*NHD + h)*NB + b] = __float2bfloat16(zv);
    }
}

// T[h][b] = sum_s esb[s][b]*z[s][h][b]
__global__ __launch_bounds__(256) void k_T2(const bf16* __restrict__ z,
                                            const float* __restrict__ esb,
                                            float* __restrict__ T){
    int h = blockIdx.x;
    int b = threadIdx.x & 63;
    int sq = threadIdx.x >> 6;
    __shared__ float red[4][64];
    float acc = 0.f;
    #pragma unroll 8
    for (int s = sq*64; s < sq*64 + 64; ++s)
        acc += esb[s*NB + b]*__bfloat162float(z[((size_t)s*NHD + h)*NB + b]);
    red[sq][b] = acc; __syncthreads();
    if (sq == 0) T[h*NB + b] = red[0][b] + red[1][b] + red[2][b] + red[3][b];
}

// ctxT[i][h][b] = (T - e_i*z_i)/(Se - e_i)
__global__ __launch_bounds__(256) void k_ctx2(const bf16* __restrict__ z,
                                              const float* __restrict__ esb,
                                              const float* __restrict__ Se,
                                              const float* __restrict__ T,
                                              bf16* __restrict__ ctxT){
    int i  = blockIdx.x >> 4;
    int hb = blockIdx.x & 15;
    int b  = threadIdx.x & 63;
    float ei  = esb[i*NB + b];
    float inv = 1.0f/(Se[b] - ei);
    #pragma unroll
    for (int q = 0; q < 16; ++q){
        int h = hb*64 + q*4 + (threadIdx.x>>6);
        float zv = __bfloat162float(z[((size_t)i*NHD + h)*NB + b]);
        float cv = (T[h*NB + b] - ei*zv)*inv;
        ctxT[((size_t)i*NHD + h)*NB + b] = __float2bfloat16(cv);
    }
}

// mu/logvar final layout: out[b][t][1024] from hh[dir][t][j][b]
__global__ __launch_bounds__(256) void k_outT(const float* __restrict__ hh,
                                              float* __restrict__ outMu,
                                              float* __restrict__ outLv){
    int bx = blockIdx.x;
    int dir = bx >> 11;
    int t  = (bx >> 3) & 255;
    int jb = bx & 7;
    int j0 = jb*64;
    __shared__ float ls[64*65];
    int tid = threadIdx.x;
    #pragma unroll
    for (int q = 0; q < 16; ++q){
        int jj = q*4 + (tid>>6);
        ls[jj*65 + (tid&63)] = hh[(((size_t)dir*NS + t)*NHE + j0 + jj)*NB + (tid&63)];
    }
    __syncthreads();
    float* outp = (dir < 2) ? outMu : outLv;
    int colbase = (dir & 1)*512;
    #pragma unroll
    for (int q = 0; q < 16; ++q){
        int bb = q*4 + (tid>>6);
        int jj = tid & 63;
        outp[((size_t)bb*NS + t)*NHD + colbase + j0 + jj] = ls[jj*65 + bb];
    }
}

// ---------------- GEMM kernels (fp32 VALU, 64x64 tiles, 4x4/thread) ----------------
__global__ __launch_bounds__(256) void k_gemm_xg(
    const float* __restrict__ x,
    const float* __restrict__ W0, const float* __restrict__ W1,
    const float* __restrict__ W2, const float* __restrict__ W3,
    const float* __restrict__ b0, const float* __restrict__ b1,
    const float* __restrict__ b2, const float* __restrict__ b3,
    bf16* __restrict__ Xg){
    int t = blockIdx.x;
    int g0 = blockIdx.y*64;
    int dir = blockIdx.z;
    const float* W   = dir==0?W0:dir==1?W1:dir==2?W2:W3;
    const float* bih = dir==0?b0:dir==1?b1:dir==2?b2:b3;
    __shared__ float As[64][36];
    __shared__ float Bs[64][36];
    int tid = threadIdx.x, tx = tid & 15, ty = tid >> 4;
    float acc[4][4] = {};
    for (int k0 = 0; k0 < ND; k0 += 32){
        #pragma unroll
        for (int m = 0; m < 8; ++m){
            int idx = m*256 + tid;
            int row = idx >> 5, kk = idx & 31;
            As[row][kk] = x[((size_t)row*NS + t)*ND + k0 + kk];
            Bs[row][kk] = W[(size_t)(g0+row)*ND + k0 + kk];
        }
        __syncthreads();
        #pragma unroll
        for (int k4 = 0; k4 < 8; ++k4){
            float4 a[4], bb[4];
            #pragma unroll
            for (int i = 0; i < 4; ++i) a[i]  = *(const float4*)&As[ty*4+i][k4*4];
            #pragma unroll
            for (int j = 0; j < 4; ++j) bb[j] = *(const float4*)&Bs[tx*4+j][k4*4];
            #pragma unroll
            for (int i = 0; i < 4; ++i)
                #pragma unroll
                for (int j = 0; j < 4; ++j)
                    acc[i][j] += a[i].x*bb[j].x + a[i].y*bb[j].y + a[i].z*bb[j].z + a[i].w*bb[j].w;
        }
        __syncthreads();
    }
    size_t base = ((size_t)(dir*NS + t)*NGE + g0)*NB;
    #pragma unroll
    for (int j = 0; j < 4; ++j){
        float bi = bih[g0 + tx*4 + j];
        #pragma unroll
        for (int i = 0; i < 4; ++i)
            Xg[base + (size_t)(tx*4+j)*NB + ty*4 + i] = __float2bfloat16(acc[i][j] + bi);
    }
}

__global__ __launch_bounds__(256) void k_gemm_gctx(
    const bf16* __restrict__ ctxT,
    const float* __restrict__ Whh,
    const float* __restrict__ bhh,
    bf16* __restrict__ Gctx){
    int i = blockIdx.x;
    int g0 = blockIdx.y*64;
    __shared__ float As[64][36];   // [b][k]
    __shared__ float Bs[64][36];   // [g][k]
    int tid = threadIdx.x, tx = tid & 15, ty = tid >> 4;
    float acc[4][4] = {};
    for (int k0 = 0; k0 < NHD; k0 += 32){
        #pragma unroll
        for (int m = 0; m < 8; ++m){
            int idx = m*256 + tid;
            int bb2 = idx & 63, kk = idx >> 6;
            As[bb2][kk] = __bfloat162float(ctxT[((size_t)i*NHD + k0 + kk)*NB + bb2]);
            int row = idx >> 5, k2 = idx & 31;
            Bs[row][k2] = Whh[(size_t)(g0+row)*NHD + k0 + k2];
        }
        __syncthreads();
        #pragma unroll
        for (int k4 = 0; k4 < 8; ++k4){
            float4 a[4], bb[4];
            #pragma unroll
            for (int i2 = 0; i2 < 4; ++i2) a[i2]  = *(const float4*)&As[ty*4+i2][k4*4];
            #pragma unroll
            for (int j = 0; j < 4; ++j)   bb[j] = *(const float4*)&Bs[tx*4+j][k4*4];
            #pragma unroll
            for (int i2 = 0; i2 < 4; ++i2)
                #pragma unroll
                for (int j = 0; j < 4; ++j)
                    acc[i2][j] += a[i2].x*bb[j].x + a[i2].y*bb[j].y + a[i2].z*bb[j].z + a[i2].w*bb[j].w;
        }
        __syncthreads();
    }
    size_t base = ((size_t)i*NGD + g0)*NB;
    #pragma unroll
    for (int j = 0; j < 4; ++j){
        float bi = bhh[g0 + tx*4 + j];
        #pragma unroll
        for (int i2 = 0; i2 < 4; ++i2)
            Gctx[base + (size_t)(tx*4+j)*NB + ty*4 + i2] = __float2bfloat16(acc[i2][j] + bi);
    }
}

__global__ __launch_bounds__(256) void k_gemm_rec(
    const float* __restrict__ H,       // [i][k][b]
    const float* __restrict__ linW,    // [512][1024]
    const float* __restrict__ linb,
    float* __restrict__ outRec){
    int i = blockIdx.x;
    int d0 = blockIdx.y*64;
    __shared__ float As[64][36];
    __shared__ float Bs[64][36];
    int tid = threadIdx.x, tx = tid & 15, ty = tid >> 4;
    float acc[4][4] = {};
    for (int k0 = 0; k0 < NHD; k0 += 32){
        #pragma unroll
        for (int m = 0; m < 8; ++m){
            int idx = m*256 + tid;
            int bb2 = idx & 63, kk = idx >> 6;
            As[bb2][kk] = H[((size_t)i*NHD + k0 + kk)*NB + bb2];
            int row = idx >> 5, k2 = idx & 31;
            Bs[row][k2] = linW[(size_t)(d0+row)*NHD + k0 + k2];
        }
        __syncthreads();
        #pragma unroll
        for (int k4 = 0; k4 < 8; ++k4){
            float4 a[4], bb[4];
            #pragma unroll
            for (int i2 = 0; i2 < 4; ++i2) a[i2]  = *(const float4*)&As[ty*4+i2][k4*4];
            #pragma unroll
            for (int j = 0; j < 4; ++j)   bb[j] = *(const float4*)&Bs[tx*4+j][k4*4];
            #pragma unroll
            for (int i2 = 0; i2 < 4; ++i2)
                #pragma unroll
                for (int j = 0; j < 4; ++j)
                    acc[i2][j] += a[i2].x*bb[j].x + a[i2].y*bb[j].y + a[i2].z*bb[j].z + a[i2].w*bb[j].w;
        }
        __syncthreads();
    }
    #pragma unroll
    for (int j = 0; j < 4; ++j){
        float lb = linb[d0 + tx*4 + j];
        #pragma unroll
        for (int i2 = 0; i2 < 4; ++i2){
            int bb2 = ty*4 + i2;
            outRec[((size_t)bb2*NS + i)*ND + d0 + tx*4 + j] = acc[i2][j] + lb;
        }
    }
}

__global__ __launch_bounds__(256) void k_gemm_M(
    const float* __restrict__ dWih,
    const float* __restrict__ linW,
    float* __restrict__ M){
    int g0 = blockIdx.x*64;
    int h0 = blockIdx.y*64;
    __shared__ float As[64][36];   // [g][k]
    __shared__ float Bs[32][68];   // [k][h]
    int tid = threadIdx.x, tx = tid & 15, ty = tid >> 4;
    float acc[4][4] = {};
    for (int k0 = 0; k0 < ND; k0 += 32){
        #pragma unroll
        for (int m = 0; m < 8; ++m){
            int idx = m*256 + tid;
            int row = idx >> 5, kk = idx & 31;
            As[row][kk] = dWih[(size_t)(g0+row)*ND + k0 + kk];
            int k2 = idx >> 6, hh2 = idx & 63;
            Bs[k2][hh2] = linW[(size_t)(k0+k2)*NHD + h0 + hh2];
        }
        __syncthreads();
        for (int k = 0; k < 32; ++k){
            float a[4];
            #pragma unroll
            for (int i = 0; i < 4; ++i) a[i] = As[ty*4+i][k];
            float4 b4 = *(const float4*)&Bs[k][tx*4];
            #pragma unroll
            for (int i = 0; i < 4; ++i){
                acc[i][0] += a[i]*b4.x; acc[i][1] += a[i]*b4.y;
                acc[i][2] += a[i]*b4.z; acc[i][3] += a[i]*b4.w;
            }
        }
        __syncthreads();
    }
    #pragma unroll
    for (int i = 0; i < 4; ++i)
        #pragma unroll
        for (int j = 0; j < 4; ++j)
            M[(size_t)(g0+ty*4+i)*NHD + h0 + tx*4 + j] = acc[i][j];
}

// ---------------- persistent cooperative recurrence kernels ----------------
// encoder: 256 WGs = 4 dirs x 64 col-groups; wave = 64 batch lanes x 2 h-cols
__global__ __launch_bounds__(256) void k_encoder2(
    const bf16* __restrict__ Xg,
    const float* __restrict__ W0, const float* __restrict__ W1,
    const float* __restrict__ W2, const float* __restrict__ W3,
    const float* __restrict__ b0, const float* __restrict__ b1,
    const float* __restrict__ b2, const float* __restrict__ b3,
    float* __restrict__ hh){   // [4][256][512][64]
    cg::grid_group grid = cg::this_grid();
    int dir = blockIdx.x & 3;
    int wgj = blockIdx.x >> 2;
    int b   = threadIdx.x & 63;
    int tc  = __builtin_amdgcn_readfirstlane(threadIdx.x >> 6);
    int jA  = wgj*8 + tc*2;
    const float* Whh = dir==0?W0:dir==1?W1:dir==2?W2:W3;
    const float* bhh = dir==0?b0:dir==1?b1:dir==2?b2:b3;
    const float* wr0 = Whh + (size_t)jA*NHE;
    const float* wz0 = Whh + (size_t)(jA+512)*NHE;
    const float* wn0 = Whh + (size_t)(jA+1024)*NHE;
    const float* wr1 = Whh + (size_t)(jA+1)*NHE;
    const float* wz1 = Whh + (size_t)(jA+513)*NHE;
    const float* wn1 = Whh + (size_t)(jA+1025)*NHE;
    float br0 = bhh[jA],   bz0 = bhh[jA+512],  bn0 = bhh[jA+1024];
    float br1 = bhh[jA+1], bz1 = bhh[jA+513],  bn1 = bhh[jA+1025];
    __shared__ float hs[64*132];
    int tid = threadIdx.x;
    float hp0 = 0.f, hp1 = 0.f;   // own previous h (wave owns its cols)
    for (int t = 0; t < NS; ++t){
        int tcur = (dir & 1) ? (255 - t) : t;
        float acc0=0,acc1=0,acc2=0,acc3=0,acc4=0,acc5=0;
        size_t xgb = ((size_t)(dir*NS + tcur)*NGE)*NB + b;
        float gi0r = __bfloat162float(Xg[xgb + (size_t)jA*NB]);
        float gi0z = __bfloat162float(Xg[xgb + (size_t)(jA+512)*NB]);
        float gi0n = __bfloat162float(Xg[xgb + (size_t)(jA+1024)*NB]);
        float gi1r = __bfloat162float(Xg[xgb + (size_t)(jA+1)*NB]);
        float gi1z = __bfloat162float(Xg[xgb + (size_t)(jA+513)*NB]);
        float gi1n = __bfloat162float(Xg[xgb + (size_t)(jA+1025)*NB]);
        if (t > 0){
            int tprev = (dir & 1) ? (256 - t) : (t - 1);
            const float* hp = hh + ((size_t)(dir*NS + tprev)*NHE)*NB;
            for (int c = 0; c < 4; ++c){
                __syncthreads();
                #pragma unroll
                for (int q = 0; q < 8; ++q){
                    int idx = q*256 + tid;
                    int kk = idx >> 4, b4 = (idx & 15)*4;
                    float4 v = *(const float4*)(hp + (size_t)(c*128 + kk)*NB + b4);
                    hs[(b4+0)*132 + kk] = v.x;
                    hs[(b4+1)*132 + kk] = v.y;
                    hs[(b4+2)*132 + kk] = v.z;
                    hs[(b4+3)*132 + kk] = v.w;
                }
                __syncthreads();
                const float* hrow = &hs[b*132];
                int kb = c*128;
                #pragma unroll 4
                for (int kq = 0; kq < 32; ++kq){
                    float4 h4 = *(const float4*)(hrow + kq*4);
                    float4 wa = *(const float4*)(wr0 + kb + kq*4);
                    float4 wb = *(const float4*)(wz0 + kb + kq*4);
                    float4 wc = *(const float4*)(wn0 + kb + kq*4);
                    float4 wd = *(const float4*)(wr1 + kb + kq*4);
                    float4 we = *(const float4*)(wz1 + kb + kq*4);
                    float4 wf = *(const float4*)(wn1 + kb + kq*4);
                    acc0 += h4.x*wa.x + h4.y*wa.y + h4.z*wa.z + h4.w*wa.w;
                    acc1 += h4.x*wb.x + h4.y*wb.y + h4.z*wb.z + h4.w*wb.w;
                    acc2 += h4.x*wc.x + h4.y*wc.y + h4.z*wc.z + h4.w*wc.w;
                    acc3 += h4.x*wd.x + h4.y*wd.y + h4.z*wd.z + h4.w*wd.w;
                    acc4 += h4.x*we.x + h4.y*we.y + h4.z*we.z + h4.w*we.w;
                    acc5 += h4.x*wf.x + h4.y*wf.y + h4.z*wf.z + h4.w*wf.w;
                }
            }
        }
        {
            float r  = sigmf(gi0r + acc0 + br0);
            float zg = sigmf(gi0z + acc1 + bz0);
            float n  = tanhf(gi0n + r*(acc2 + bn0));
            hp0 = (1.0f - zg)*n + zg*hp0;
        }
        {
            float r  = sigmf(gi1r + acc3 + br1);
            float zg = sigmf(gi1z + acc4 + bz1);
            float n  = tanhf(gi1n + r*(acc5 + bn1));
            hp1 = (1.0f - zg)*n + zg*hp1;
        }
        float* ho = hh + ((size_t)(dir*NS + tcur)*NHE)*NB;
        ho[(size_t)jA*NB + b]     = hp0;
        ho[(size_t)(jA+1)*NB + b] = hp1;
        grid.sync();
    }
}

// decoder: 256 WGs x 4 gate-triples; gi via M-composition
__global__ __launch_bounds__(256) void k_decoder2(
    const float* __restrict__ M,
    const float* __restrict__ cvec,
    const float* __restrict__ dbih,
    const bf16* __restrict__ Gctx,
    const bf16* __restrict__ ctxT,
    float* __restrict__ H){
    cg::grid_group grid = cg::this_grid();
    int b  = threadIdx.x & 63;
    int tc = __builtin_amdgcn_readfirstlane(threadIdx.x >> 6);
    int j  = blockIdx.x*4 + tc;
    const float* m0 = M + (size_t)j*NHD;
    const float* m1 = M + (size_t)(j+NHD)*NHD;
    const float* m2 = M + (size_t)(j+2*NHD)*NHD;
    float c0 = cvec[j], c1 = cvec[j+NHD], c2 = cvec[j+2*NHD];
    float d0 = dbih[j], d1 = dbih[j+NHD], d2 = dbih[j+2*NHD];
    __shared__ float hs[64*132];
    int tid = threadIdx.x;
    for (int i = 0; i < NS; ++i){
        size_t gb = (size_t)i*NGD*NB + b;
        float ghr = __bfloat162float(Gctx[gb + (size_t)j*NB]);
        float ghz = __bfloat162float(Gctx[gb + (size_t)(j+NHD)*NB]);
        float ghn = __bfloat162float(Gctx[gb + (size_t)(j+2*NHD)*NB]);
        float cv  = __bfloat162float(ctxT[((size_t)i*NHD + j)*NB + b]);
        float g0, g1, g2;
        if (i == 0){ g0 = d0; g1 = d1; g2 = d2; }
        else {
            const float* hp = H + (size_t)(i-1)*NHD*NB;
            float a0=0, a1=0, a2=0;
            for (int c = 0; c < 8; ++c){
                __syncthreads();
                #pragma unroll
                for (int q = 0; q < 8; ++q){
                    int idx = q*256 + tid;
                    int kk = idx >> 4, b4 = (idx & 15)*4;
                    float4 v = *(const float4*)(hp + (size_t)(c*128 + kk)*NB + b4);
                    hs[(b4+0)*132 + kk] = v.x;
                    hs[(b4+1)*132 + kk] = v.y;
                    hs[(b4+2)*132 + kk] = v.z;
                    hs[(b4+3)*132 + kk] = v.w;
                }
                __syncthreads();
                const float* hrow = &hs[b*132];
                int kb = c*128;
                #pragma unroll 4
                for (int kq = 0; kq < 32; ++kq){
                    float4 h4 = *(const float4*)(hrow + kq*4);
                    float4 wa = *(const float4*)(m0 + kb + kq*4);
                    float4 wb = *(const float4*)(m1 + kb + kq*4);
                    float4 wc = *(const float4*)(m2 + kb + kq*4);
                    a0 += h4.x*wa.x + h4.y*wa.y + h4.z*wa.z + h4.w*wa.w;
                    a1 += h4.x*wb.x + h4.y*wb.y + h4.z*wb.z + h4.w*wb.w;
                    a2 += h4.x*wc.x + h4.y*wc.y + h4.z*wc.z + h4.w*wc.w;
                }
            }
            g0 = a0 + c0; g1 = a1 + c1; g2 = a2 + c2;
        }
        float r  = sigmf(g0 + ghr);
        float zg = sigmf(g1 + ghz);
        float n  = tanhf(g2 + r*ghn);
        float hn = (1.0f - zg)*n + zg*cv;
        H[((size_t)i*NHD + j)*NB + b] = hn;
        grid.sync();
    }
}

// ---------------- host launcher ----------------
extern "C" void kernel_launch(void* const* d_in, const int* in_sizes, int n_in,
                              void* d_out, int out_size, void* d_ws, size_t ws_size,
                              hipStream_t stream){
    const float* x   = (const float*)d_in[0];
    const float* eps = (const float*)d_in[1];
    const float* Wih[4]; const float* Whh[4]; const float* bih[4]; const float* bhh[4];
    for (int d = 0; d < 4; ++d){
        Wih[d] = (const float*)d_in[2 + 4*d];
        Whh[d] = (const float*)d_in[3 + 4*d];
        bih[d] = (const float*)d_in[4 + 4*d];
        bhh[d] = (const float*)d_in[5 + 4*d];
    }
    const float* dWih  = (const float*)d_in[18];
    const float* dWhh  = (const float*)d_in[19];
    const float* dbih  = (const float*)d_in[20];
    const float* dbhh  = (const float*)d_in[21];
    const float* attnW = (const float*)d_in[22];
    const float* attnb = (const float*)d_in[23];
    const float* linW  = (const float*)d_in[24];
    const float* linb  = (const float*)d_in[25];

    float* out    = (float*)d_out;
    float* outRec = out;
    float* outMu  = out + 8388608;
    float* outLv  = out + 25165824;

    char* ws = (char*)d_ws;
    bf16*  Xg    = (bf16*)(ws + 0);              // 201326592   (dead after encoder)
    bf16*  Gctx  = (bf16*)(ws + 0);              // 100663296   (reuses Xg space)
    float* Hdec  = (float*)(ws + 100663296);     // 67108864    (reuses Xg space)
    float* hh    = (float*)(ws + 201326592);     // 134217728
    bf16*  zbuf  = (bf16*)(ws + 335544320);      // 33554432
    bf16*  ctxT  = (bf16*)(ws + 369098752);      // 33554432
    float* Mbuf  = (float*)(ws + 402653184);     // 12582912
    float* sx    = (float*)(ws + 415236096);     // 65536
    float* esb   = (float*)(ws + 415301632);     // 65536
    float* Se    = (float*)(ws + 415367168);     // 4096
    float* Tbuf  = (float*)(ws + 415371264);     // 262144
    float* cvec  = (float*)(ws + 415633408);     // 12288

    // phase 0: parallel prep
    hipLaunchKernelGGL(k_gemm_M, dim3(48,16), dim3(256), 0, stream, dWih, linW, Mbuf);
    hipLaunchKernelGGL(k_cvec, dim3(768), dim3(256), 0, stream, dWih, linb, dbih, cvec);
    hipLaunchKernelGGL(k_sx, dim3(4096), dim3(256), 0, stream, x, attnW, attnb, sx);
    hipLaunchKernelGGL(k_softprep2, dim3(64), dim3(256), 0, stream, sx, esb, Se);
    hipLaunchKernelGGL(k_gemm_xg, dim3(256,24,4), dim3(256), 0, stream,
                       x, Wih[0], Wih[1], Wih[2], Wih[3], bih[0], bih[1], bih[2], bih[3], Xg);

    // phase 1: encoder recurrence -> hh
    {
        void* a[] = { (void*)&Xg, (void*)&Whh[0], (void*)&Whh[1], (void*)&Whh[2], (void*)&Whh[3],
                      (void*)&bhh[0], (void*)&bhh[1], (void*)&bhh[2], (void*)&bhh[3], (void*)&hh };
        hipLaunchCooperativeKernel((void*)k_encoder2, dim3(256), dim3(256), a, 0, stream);
    }

    // phase 2: z, attention statics, Gctx; mu/logvar output transpose
    hipLaunchKernelGGL(k_zexp2, dim3(4096), dim3(256), 0, stream, hh, eps, zbuf);
    hipLaunchKernelGGL(k_outT, dim3(8192), dim3(256), 0, stream, hh, outMu, outLv);
    hipLaunchKernelGGL(k_T2, dim3(1024), dim3(256), 0, stream, zbuf, esb, Tbuf);
    hipLaunchKernelGGL(k_ctx2, dim3(4096), dim3(256), 0, stream, zbuf, esb, Se, Tbuf, ctxT);
    hipLaunchKernelGGL(k_gemm_gctx, dim3(256,48), dim3(256), 0, stream, ctxT, dWhh, dbhh, Gctx);

    // phase 3: decoder recurrence
    {
        void* a[] = { (void*)&Mbuf, (void*)&cvec, (void*)&dbih, (void*)&Gctx, (void*)&ctxT, (void*)&Hdec };
        hipLaunchCooperativeKernel((void*)k_decoder2, dim3(256), dim3(256), a, 0, stream);
    }

    // phase 4: output projection
    hipLaunchKernelGGL(k_gemm_rec, dim3(256,8), dim3(256), 0, stream, Hdec, linW, linb, outRec);
}